// Round 6
// baseline (152.640 us; speedup 1.0000x reference)
//
#include <hip/hip_runtime.h>
#include <hip/hip_bf16.h>

// SDPA, causal, b=16 t=2048 d=64. Outputs FP32: d_out = [ out | sm_qk ].
// 4 waves/block, QB=64. Two-phase (rowsum; recompute+emit).
// R6: phase 1 is barrier-free — K B-frags loaded directly from global
// (L1/L2-resident via XCD batch clustering), no LDS, no __syncthreads;
// waves drift freely. Phase 2 keeps reg-prefetch + LDS staging + split-bf16
// compensated QK^T for the emitted P.

#define BATCHES 16
#define SEQ 2048
#define DIM 64
#define QB 64
#define KT 64
#define NQB (SEQ / QB) /* 32 */
#define KLD 72   /* K LDS row stride, shorts */
#define VLD 72   /* V^T LDS row stride, shorts */
#define PFLD 68  /* P LDS row stride, floats */

typedef __attribute__((ext_vector_type(8))) short bf16x8;
typedef __attribute__((ext_vector_type(4))) short short4v;
typedef __attribute__((ext_vector_type(4))) float f32x4;

static __device__ __forceinline__ short f2bf(float f) {
    return __builtin_bit_cast(short, __float2bfloat16(f));
}
static __device__ __forceinline__ float bf2f(short s) {
    unsigned int u = ((unsigned int)(unsigned short)s) << 16;
    return __builtin_bit_cast(float, u);
}
static __device__ __forceinline__ bf16x8 pack8(f32x4 a, f32x4 b) {
    bf16x8 r;
    r[0] = f2bf(a[0]); r[1] = f2bf(a[1]); r[2] = f2bf(a[2]); r[3] = f2bf(a[3]);
    r[4] = f2bf(b[0]); r[5] = f2bf(b[1]); r[6] = f2bf(b[2]); r[7] = f2bf(b[3]);
    return r;
}
static __device__ __forceinline__ void split8(f32x4 a, f32x4 b, float sc,
                                              bf16x8& h, bf16x8& l) {
#pragma unroll
    for (int e = 0; e < 4; ++e) {
        float x = a[e] * sc;
        short hb = f2bf(x);
        h[e] = hb; l[e] = f2bf(x - bf2f(hb));
    }
#pragma unroll
    for (int e = 0; e < 4; ++e) {
        float x = b[e] * sc;
        short hb = f2bf(x);
        h[4 + e] = hb; l[4 + e] = f2bf(x - bf2f(hb));
    }
}

__global__ __launch_bounds__(256, 3) void sdpa_fused(
    const float* __restrict__ Qg, const float* __restrict__ Kg,
    const float* __restrict__ Vg, float* __restrict__ Og, float* __restrict__ Pg)
{
    // 1D grid 512. XCD = i%8; XCD g owns batches {2g,2g+1}.
    // Pairing (qb=c, b=2g)+(qb=31-c, b=2g+1) balances causal work per CU.
    const int i = blockIdx.x;
    const int g = i & 7;
    const int j = i >> 3;             // 0..63
    const int b = 2 * g + (j >> 5);
    const int jj = j & 31;
    const int qb = (j < 32) ? jj : (31 - jj);
    const int q0 = qb * QB;

    const int tid = threadIdx.x;
    const int lane = tid & 63;
    const int wave = tid >> 6;        // wave owns q-rows [wave*16, wave*16+16)
    const int lo = lane & 15;
    const int hi = lane >> 4;
    const int sr = tid >> 4;          // stage row base (K)
    const int sc = (tid & 15) * 4;    // stage col
    const int vr = (tid >> 4) * 4;    // stage rows (V)

    __shared__ short Khi[KT * KLD];
    __shared__ short Klo[KT * KLD];
    __shared__ short Vt[DIM * VLD];
    __shared__ float Pf[QB * PFLD];

    const float* qB = Qg + (size_t)b * SEQ * DIM;
    const float* kB = Kg + (size_t)b * SEQ * DIM;
    const float* vB = Vg + (size_t)b * SEQ * DIM;

    // Q A-frags, scale 1/8, hi/lo split
    bf16x8 qa0h, qa0l, qa1h, qa1l;
    {
        const float* qr = &qB[(size_t)(q0 + wave * 16 + lo) * DIM + hi * 8];
        split8(*(const f32x4*)qr,        *(const f32x4*)(qr + 4),  0.125f, qa0h, qa0l);
        split8(*(const f32x4*)(qr + 32), *(const f32x4*)(qr + 36), 0.125f, qa1h, qa1l);
    }

    const int nkt = qb + 1;
    float rl[4] = {0.f, 0.f, 0.f, 0.f};

    // ====== phase 1: l = sum exp(S); barrier-free, K direct from global ======
    for (int kt = 0; kt < nkt; ++kt) {
        const int nmax = (kt == qb) ? (wave + 1) : 4;
        for (int n = 0; n < nmax; ++n) {
            const float* kr = &kB[(size_t)(kt * KT + 16 * n + lo) * DIM + hi * 8];
            bf16x8 kb0 = pack8(*(const f32x4*)kr,        *(const f32x4*)(kr + 4));
            bf16x8 kb1 = pack8(*(const f32x4*)(kr + 32), *(const f32x4*)(kr + 36));
            f32x4 acc = {0.f, 0.f, 0.f, 0.f};
            acc = __builtin_amdgcn_mfma_f32_16x16x32_bf16(qa0h, kb0, acc, 0, 0, 0);
            acc = __builtin_amdgcn_mfma_f32_16x16x32_bf16(qa1h, kb1, acc, 0, 0, 0);
            if (kt < qb) {
#pragma unroll
                for (int jx = 0; jx < 4; ++jx) rl[jx] += __expf(acc[jx]);
            } else {
                const int col = 16 * n + lo;
#pragma unroll
                for (int jx = 0; jx < 4; ++jx)
                    if (col <= wave * 16 + hi * 4 + jx) rl[jx] += __expf(acc[jx]);
            }
        }
    }
#pragma unroll
    for (int m = 1; m <= 8; m <<= 1)
#pragma unroll
        for (int jx = 0; jx < 4; ++jx) rl[jx] += __shfl_xor(rl[jx], m, 16);
    float il[4];
#pragma unroll
    for (int jx = 0; jx < 4; ++jx) il[jx] = 1.0f / rl[jx];

    // ============ phase 2: P = exp(S)/l (fp32) + O = P*V ============
    f32x4 o[4];
#pragma unroll
    for (int n = 0; n < 4; ++n) { o[n][0] = 0.f; o[n][1] = 0.f; o[n][2] = 0.f; o[n][3] = 0.f; }

    f32x4 kp2[4], vp2[4];
#pragma unroll
    for (int ii = 0; ii < 4; ++ii) {
        kp2[ii] = *(const f32x4*)&kB[(size_t)(sr + 16 * ii) * DIM + sc];
        vp2[ii] = *(const f32x4*)&vB[(size_t)(vr + ii) * DIM + sc];
    }

    for (int kt = 0; kt < nkt; ++kt) {
        __syncthreads();
        {   // stage K (split hi/lo) and V (transposed) from prefetched regs
#pragma unroll
            for (int ii = 0; ii < 4; ++ii) {
                short4v hh, ll;
#pragma unroll
                for (int e = 0; e < 4; ++e) {
                    short hb = f2bf(kp2[ii][e]);
                    hh[e] = hb; ll[e] = f2bf(kp2[ii][e] - bf2f(hb));
                }
                *(short4v*)&Khi[(sr + 16 * ii) * KLD + sc] = hh;
                *(short4v*)&Klo[(sr + 16 * ii) * KLD + sc] = ll;
            }
#pragma unroll
            for (int e = 0; e < 4; ++e) {      // 4x4 in-register transpose
                short4v tv;
#pragma unroll
                for (int ii = 0; ii < 4; ++ii) tv[ii] = f2bf(vp2[ii][e]);
                *(short4v*)&Vt[(sc + e) * VLD + vr] = tv;
            }
        }
        __syncthreads();
        if (kt + 1 < nkt) {                    // prefetch next K,V
#pragma unroll
            for (int ii = 0; ii < 4; ++ii) {
                kp2[ii] = *(const f32x4*)&kB[(size_t)((kt + 1) * KT + sr + 16 * ii) * DIM + sc];
                vp2[ii] = *(const f32x4*)&vB[(size_t)((kt + 1) * KT + vr + ii) * DIM + sc];
            }
        }
        // S = QK^T (compensated), P into fp32 LDS tile
#pragma unroll
        for (int n = 0; n < 4; ++n) {
            const bool fm = (kt == qb) && (n > wave);  // wave-uniform
            f32x4 acc = {0.f, 0.f, 0.f, 0.f};
            if (!fm) {
                bf16x8 kh0 = *(const bf16x8*)&Khi[(16 * n + lo) * KLD + hi * 8];
                bf16x8 kh1 = *(const bf16x8*)&Khi[(16 * n + lo) * KLD + 32 + hi * 8];
                bf16x8 kl0 = *(const bf16x8*)&Klo[(16 * n + lo) * KLD + hi * 8];
                bf16x8 kl1 = *(const bf16x8*)&Klo[(16 * n + lo) * KLD + 32 + hi * 8];
                acc = __builtin_amdgcn_mfma_f32_16x16x32_bf16(qa0h, kh0, acc, 0, 0, 0);
                acc = __builtin_amdgcn_mfma_f32_16x16x32_bf16(qa1h, kh1, acc, 0, 0, 0);
                acc = __builtin_amdgcn_mfma_f32_16x16x32_bf16(qa0h, kl0, acc, 0, 0, 0);
                acc = __builtin_amdgcn_mfma_f32_16x16x32_bf16(qa1h, kl1, acc, 0, 0, 0);
                acc = __builtin_amdgcn_mfma_f32_16x16x32_bf16(qa0l, kh0, acc, 0, 0, 0);
                acc = __builtin_amdgcn_mfma_f32_16x16x32_bf16(qa1l, kh1, acc, 0, 0, 0);
            }
            const int col = 16 * n + lo;
#pragma unroll
            for (int jx = 0; jx < 4; ++jx) {
                const int row = wave * 16 + hi * 4 + jx;
                const float p = (!fm && (kt < qb || col <= row)) ? __expf(acc[jx]) * il[jx] : 0.f;
                Pf[row * PFLD + col] = p;
            }
        }
        // stream own P band to global (issue stores before PV)
        {
            const int r = wave * 16 + (lane >> 2);
            const int cb = (lane & 3) * 16;
            float* dst = &Pg[((size_t)(b * SEQ) + q0 + r) * SEQ + kt * KT + cb];
            const float* src = &Pf[r * PFLD + cb];
#pragma unroll
            for (int iw = 0; iw < 4; ++iw)
                *(f32x4*)&dst[4 * iw] = *(const f32x4*)&src[4 * iw];
        }
        // PV: A-frag from own Pf band (fp32->bf16), B-frag from Vt
        {
            const float* pr = &Pf[(wave * 16 + lo) * PFLD + hi * 8];
            bf16x8 pa0, pa1;
            {
                f32x4 a = *(const f32x4*)pr, c2 = *(const f32x4*)(pr + 4);
                f32x4 d = *(const f32x4*)(pr + 32), e2 = *(const f32x4*)(pr + 36);
#pragma unroll
                for (int e = 0; e < 4; ++e) {
                    pa0[e] = f2bf(a[e]); pa0[4 + e] = f2bf(c2[e]);
                    pa1[e] = f2bf(d[e]); pa1[4 + e] = f2bf(e2[e]);
                }
            }
#pragma unroll
            for (int n = 0; n < 4; ++n) {
                bf16x8 vb0 = *(const bf16x8*)&Vt[(16 * n + lo) * VLD + hi * 8];
                bf16x8 vb1 = *(const bf16x8*)&Vt[(16 * n + lo) * VLD + 32 + hi * 8];
                o[n] = __builtin_amdgcn_mfma_f32_16x16x32_bf16(pa0, vb0, o[n], 0, 0, 0);
                o[n] = __builtin_amdgcn_mfma_f32_16x16x32_bf16(pa1, vb1, o[n], 0, 0, 0);
            }
        }
    }

    // ---- zero-fill fully-masked column tiles (exact 0 == ref underflow) ----
    {
        const int r = tid >> 2;
        float* rowp = &Pg[((size_t)(b * SEQ) + q0 + r) * SEQ];
        const f32x4 z = {0.f, 0.f, 0.f, 0.f};
        for (int cb = nkt * KT + (tid & 3) * 16; cb < SEQ; cb += KT)
#pragma unroll
            for (int iw = 0; iw < 4; ++iw)
                *(f32x4*)&rowp[cb + 4 * iw] = z;
    }
    // ---- O (already normalized), fp32 ----
    {
        float* og = &Og[((size_t)(b * SEQ) + q0 + wave * 16 + hi * 4) * DIM + lo];
#pragma unroll
        for (int jx = 0; jx < 4; ++jx)
#pragma unroll
            for (int n = 0; n < 4; ++n)
                og[jx * DIM + n * 16] = o[n][jx];
    }
}

extern "C" void kernel_launch(void* const* d_in, const int* in_sizes, int n_in,
                              void* d_out, int out_size, void* d_ws, size_t ws_size,
                              hipStream_t stream) {
    const float* q = (const float*)d_in[0];
    const float* k = (const float*)d_in[1];
    const float* v = (const float*)d_in[2];
    float* out  = (float*)d_out;                        // [B,T,D] fp32
    float* smqk = out + (size_t)BATCHES * SEQ * DIM;    // [B,T,T] fp32

    sdpa_fused<<<NQB * BATCHES, 256, 0, stream>>>(q, k, v, out, smqk);
}

// Round 8
// 147.580 us; speedup vs baseline: 1.0343x; 1.0343x over previous
//
#include <hip/hip_runtime.h>
#include <hip/hip_bf16.h>

// SDPA, causal, b=16 t=2048 d=64. Outputs FP32: d_out = [ out | sm_qk ].
// R8 = R7 with the Pb stride bug fixed (40 -> 72; KT=64 needs >=64+pad).
//  Kernel A (grid 512): single-pass flash: compensated S, l & unnormalized O
//    accumulated together, O=o*il written, il -> d_ws, masked-P zero-fill.
//  Kernel B (grid 768, kv-chunked): P = exp(S)*il emission only (no O).
// Both: XCD batch clustering (block i -> XCD i%8 owning batches {2g,2g+1}),
// reg-prefetch staging, split-bf16 compensated QK^T (qh*kh+qh*kl+ql*kh).

#define BATCHES 16
#define SEQ 2048
#define DIM 64
#define QB 64
#define KT 64
#define NQB (SEQ / QB) /* 32 */
#define KLD 72   /* K LDS row stride, shorts */
#define VLD 72   /* V^T LDS row stride, shorts */
#define PBLD 72  /* A: bf16 P-tile stride, shorts (64 cols + pad) */
#define PFLD 68  /* B: fp32 P-tile stride, floats */

typedef __attribute__((ext_vector_type(8))) short bf16x8;
typedef __attribute__((ext_vector_type(4))) short short4v;
typedef __attribute__((ext_vector_type(4))) float f32x4;

static __device__ __forceinline__ short f2bf(float f) {
    return __builtin_bit_cast(short, __float2bfloat16(f));
}
static __device__ __forceinline__ float bf2f(short s) {
    unsigned int u = ((unsigned int)(unsigned short)s) << 16;
    return __builtin_bit_cast(float, u);
}
static __device__ __forceinline__ void split8(f32x4 a, f32x4 b, float sc,
                                              bf16x8& h, bf16x8& l) {
#pragma unroll
    for (int e = 0; e < 4; ++e) {
        float x = a[e] * sc;
        short hb = f2bf(x);
        h[e] = hb; l[e] = f2bf(x - bf2f(hb));
    }
#pragma unroll
    for (int e = 0; e < 4; ++e) {
        float x = b[e] * sc;
        short hb = f2bf(x);
        h[4 + e] = hb; l[4 + e] = f2bf(x - bf2f(hb));
    }
}

// ---------------- Kernel A: O + l (+ zero-fill of masked P) ----------------
__global__ __launch_bounds__(256, 2) void attn_ol(
    const float* __restrict__ Qg, const float* __restrict__ Kg,
    const float* __restrict__ Vg, float* __restrict__ Og,
    float* __restrict__ Pg, float* __restrict__ ilW)
{
    const int i = blockIdx.x;
    const int g = i & 7;
    const int j = i >> 3;             // 0..63
    const int b = 2 * g + (j >> 5);
    const int jj = j & 31;
    const int qb = (j < 32) ? jj : (31 - jj);
    const int q0 = qb * QB;

    const int tid = threadIdx.x;
    const int lane = tid & 63;
    const int wave = tid >> 6;
    const int lo = lane & 15;
    const int hi = lane >> 4;
    const int sr = tid >> 4;
    const int sc = (tid & 15) * 4;
    const int vr = (tid >> 4) * 4;

    __shared__ short Khi[KT * KLD];
    __shared__ short Klo[KT * KLD];
    __shared__ short Vt[DIM * VLD];
    __shared__ short Pb[QB * PBLD];    // bf16 unnormalized P (PV A-frag relay)

    const float* qB = Qg + (size_t)b * SEQ * DIM;
    const float* kB = Kg + (size_t)b * SEQ * DIM;
    const float* vB = Vg + (size_t)b * SEQ * DIM;

    bf16x8 qa0h, qa0l, qa1h, qa1l;
    {
        const float* qr = &qB[(size_t)(q0 + wave * 16 + lo) * DIM + hi * 8];
        split8(*(const f32x4*)qr,        *(const f32x4*)(qr + 4),  0.125f, qa0h, qa0l);
        split8(*(const f32x4*)(qr + 32), *(const f32x4*)(qr + 36), 0.125f, qa1h, qa1l);
    }

    const int nkt = qb + 1;
    float rl[4] = {0.f, 0.f, 0.f, 0.f};
    f32x4 o[4];
#pragma unroll
    for (int n = 0; n < 4; ++n) { o[n][0] = 0.f; o[n][1] = 0.f; o[n][2] = 0.f; o[n][3] = 0.f; }

    f32x4 kp[4], vp[4];
#pragma unroll
    for (int ii = 0; ii < 4; ++ii) {
        kp[ii] = *(const f32x4*)&kB[(size_t)(sr + 16 * ii) * DIM + sc];
        vp[ii] = *(const f32x4*)&vB[(size_t)(vr + ii) * DIM + sc];
    }

    for (int kt = 0; kt < nkt; ++kt) {
        __syncthreads();
        {   // stage K (hi/lo) + V^T from prefetched regs
#pragma unroll
            for (int ii = 0; ii < 4; ++ii) {
                short4v hh, ll;
#pragma unroll
                for (int e = 0; e < 4; ++e) {
                    short hb = f2bf(kp[ii][e]);
                    hh[e] = hb; ll[e] = f2bf(kp[ii][e] - bf2f(hb));
                }
                *(short4v*)&Khi[(sr + 16 * ii) * KLD + sc] = hh;
                *(short4v*)&Klo[(sr + 16 * ii) * KLD + sc] = ll;
            }
#pragma unroll
            for (int e = 0; e < 4; ++e) {
                short4v tv;
#pragma unroll
                for (int ii = 0; ii < 4; ++ii) tv[ii] = f2bf(vp[ii][e]);
                *(short4v*)&Vt[(sc + e) * VLD + vr] = tv;
            }
        }
        __syncthreads();
        if (kt + 1 < nkt) {
#pragma unroll
            for (int ii = 0; ii < 4; ++ii) {
                kp[ii] = *(const f32x4*)&kB[(size_t)((kt + 1) * KT + sr + 16 * ii) * DIM + sc];
                vp[ii] = *(const f32x4*)&vB[(size_t)((kt + 1) * KT + vr + ii) * DIM + sc];
            }
        }
        // S (compensated) -> p_unnorm = exp(S); accumulate l; relay via Pb
#pragma unroll
        for (int n = 0; n < 4; ++n) {
            const bool fm = (kt == qb) && (n > wave);
            f32x4 acc = {0.f, 0.f, 0.f, 0.f};
            if (!fm) {
                bf16x8 kh0 = *(const bf16x8*)&Khi[(16 * n + lo) * KLD + hi * 8];
                bf16x8 kh1 = *(const bf16x8*)&Khi[(16 * n + lo) * KLD + 32 + hi * 8];
                bf16x8 kl0 = *(const bf16x8*)&Klo[(16 * n + lo) * KLD + hi * 8];
                bf16x8 kl1 = *(const bf16x8*)&Klo[(16 * n + lo) * KLD + 32 + hi * 8];
                acc = __builtin_amdgcn_mfma_f32_16x16x32_bf16(qa0h, kh0, acc, 0, 0, 0);
                acc = __builtin_amdgcn_mfma_f32_16x16x32_bf16(qa1h, kh1, acc, 0, 0, 0);
                acc = __builtin_amdgcn_mfma_f32_16x16x32_bf16(qa0h, kl0, acc, 0, 0, 0);
                acc = __builtin_amdgcn_mfma_f32_16x16x32_bf16(qa1h, kl1, acc, 0, 0, 0);
                acc = __builtin_amdgcn_mfma_f32_16x16x32_bf16(qa0l, kh0, acc, 0, 0, 0);
                acc = __builtin_amdgcn_mfma_f32_16x16x32_bf16(qa1l, kh1, acc, 0, 0, 0);
            }
            const int col = 16 * n + lo;
#pragma unroll
            for (int jx = 0; jx < 4; ++jx) {
                const int row = wave * 16 + hi * 4 + jx;
                const float p = (!fm && (kt < qb || col <= row)) ? __expf(acc[jx]) : 0.f;
                rl[jx] += p;
                Pb[row * PBLD + col] = f2bf(p);
            }
        }
        // O += P_unnorm * V
        {
            bf16x8 pa0 = *(const bf16x8*)&Pb[(wave * 16 + lo) * PBLD + hi * 8];
            bf16x8 pa1 = *(const bf16x8*)&Pb[(wave * 16 + lo) * PBLD + 32 + hi * 8];
#pragma unroll
            for (int n = 0; n < 4; ++n) {
                bf16x8 vb0 = *(const bf16x8*)&Vt[(16 * n + lo) * VLD + hi * 8];
                bf16x8 vb1 = *(const bf16x8*)&Vt[(16 * n + lo) * VLD + 32 + hi * 8];
                o[n] = __builtin_amdgcn_mfma_f32_16x16x32_bf16(pa0, vb0, o[n], 0, 0, 0);
                o[n] = __builtin_amdgcn_mfma_f32_16x16x32_bf16(pa1, vb1, o[n], 0, 0, 0);
            }
        }
    }

    // row sums -> il; write O = o*il; stash il
#pragma unroll
    for (int m = 1; m <= 8; m <<= 1)
#pragma unroll
        for (int jx = 0; jx < 4; ++jx) rl[jx] += __shfl_xor(rl[jx], m, 16);
    float il[4];
#pragma unroll
    for (int jx = 0; jx < 4; ++jx) il[jx] = 1.0f / rl[jx];
    {
        float* og = &Og[((size_t)(b * SEQ) + q0 + wave * 16 + hi * 4) * DIM + lo];
#pragma unroll
        for (int jx = 0; jx < 4; ++jx)
#pragma unroll
            for (int n = 0; n < 4; ++n)
                og[jx * DIM + n * 16] = o[n][jx] * il[jx];
    }
    if (lo == 0) {
#pragma unroll
        for (int jx = 0; jx < 4; ++jx)
            ilW[(size_t)b * SEQ + q0 + wave * 16 + hi * 4 + jx] = il[jx];
    }
    // zero-fill fully-masked column tiles of this q-band
    {
        const int r = tid >> 2;
        float* rowp = &Pg[((size_t)(b * SEQ) + q0 + r) * SEQ];
        const f32x4 z = {0.f, 0.f, 0.f, 0.f};
        for (int cb = nkt * KT + (tid & 3) * 16; cb < SEQ; cb += KT)
#pragma unroll
            for (int iw = 0; iw < 4; ++iw)
                *(f32x4*)&rowp[cb + 4 * iw] = z;
    }
}

// ---------------- Kernel B: P emission (kv-chunked) ----------------
__global__ __launch_bounds__(256, 4) void emit_p(
    const float* __restrict__ Qg, const float* __restrict__ Kg,
    const float* __restrict__ ilW, float* __restrict__ Pg)
{
    // grid 768 = 8 XCD * 96. j=i>>3: b=2g+(j&1); idx=j>>1 in 0..47:
    // idx<32: qb=idx, tiles [0, min(qb+1,16)); idx>=32: qb=idx-16, tiles [16, qb+1)
    const int i = blockIdx.x;
    const int g = i & 7;
    const int j = i >> 3;             // 0..95
    const int b = 2 * g + (j & 1);
    const int idx = j >> 1;           // 0..47
    const int qb  = (idx < 32) ? idx : (idx - 16);
    const int kt0 = (idx < 32) ? 0 : 16;
    const int ktE = (idx < 32) ? ((qb + 1 < 16) ? qb + 1 : 16) : (qb + 1);
    const int q0 = qb * QB;

    const int tid = threadIdx.x;
    const int lane = tid & 63;
    const int wave = tid >> 6;
    const int lo = lane & 15;
    const int hi = lane >> 4;
    const int sr = tid >> 4;
    const int sc = (tid & 15) * 4;

    __shared__ short Khi[KT * KLD];
    __shared__ short Klo[KT * KLD];
    __shared__ float Pf[QB * PFLD];

    const float* qB = Qg + (size_t)b * SEQ * DIM;
    const float* kB = Kg + (size_t)b * SEQ * DIM;

    bf16x8 qa0h, qa0l, qa1h, qa1l;
    {
        const float* qr = &qB[(size_t)(q0 + wave * 16 + lo) * DIM + hi * 8];
        split8(*(const f32x4*)qr,        *(const f32x4*)(qr + 4),  0.125f, qa0h, qa0l);
        split8(*(const f32x4*)(qr + 32), *(const f32x4*)(qr + 36), 0.125f, qa1h, qa1l);
    }
    float il4[4];
#pragma unroll
    for (int jx = 0; jx < 4; ++jx)
        il4[jx] = ilW[(size_t)b * SEQ + q0 + wave * 16 + hi * 4 + jx];

    f32x4 kp[4];
#pragma unroll
    for (int ii = 0; ii < 4; ++ii)
        kp[ii] = *(const f32x4*)&kB[(size_t)(kt0 * KT + sr + 16 * ii) * DIM + sc];

    for (int kt = kt0; kt < ktE; ++kt) {
        __syncthreads();
        {
#pragma unroll
            for (int ii = 0; ii < 4; ++ii) {
                short4v hh, ll;
#pragma unroll
                for (int e = 0; e < 4; ++e) {
                    short hb = f2bf(kp[ii][e]);
                    hh[e] = hb; ll[e] = f2bf(kp[ii][e] - bf2f(hb));
                }
                *(short4v*)&Khi[(sr + 16 * ii) * KLD + sc] = hh;
                *(short4v*)&Klo[(sr + 16 * ii) * KLD + sc] = ll;
            }
        }
        __syncthreads();
        if (kt + 1 < ktE) {
#pragma unroll
            for (int ii = 0; ii < 4; ++ii)
                kp[ii] = *(const f32x4*)&kB[(size_t)((kt + 1) * KT + sr + 16 * ii) * DIM + sc];
        }
#pragma unroll
        for (int n = 0; n < 4; ++n) {
            const bool fm = (kt == qb) && (n > wave);
            f32x4 acc = {0.f, 0.f, 0.f, 0.f};
            if (!fm) {
                bf16x8 kh0 = *(const bf16x8*)&Khi[(16 * n + lo) * KLD + hi * 8];
                bf16x8 kh1 = *(const bf16x8*)&Khi[(16 * n + lo) * KLD + 32 + hi * 8];
                bf16x8 kl0 = *(const bf16x8*)&Klo[(16 * n + lo) * KLD + hi * 8];
                bf16x8 kl1 = *(const bf16x8*)&Klo[(16 * n + lo) * KLD + 32 + hi * 8];
                acc = __builtin_amdgcn_mfma_f32_16x16x32_bf16(qa0h, kh0, acc, 0, 0, 0);
                acc = __builtin_amdgcn_mfma_f32_16x16x32_bf16(qa1h, kh1, acc, 0, 0, 0);
                acc = __builtin_amdgcn_mfma_f32_16x16x32_bf16(qa0h, kl0, acc, 0, 0, 0);
                acc = __builtin_amdgcn_mfma_f32_16x16x32_bf16(qa1h, kl1, acc, 0, 0, 0);
                acc = __builtin_amdgcn_mfma_f32_16x16x32_bf16(qa0l, kh0, acc, 0, 0, 0);
                acc = __builtin_amdgcn_mfma_f32_16x16x32_bf16(qa1l, kh1, acc, 0, 0, 0);
            }
            const int col = 16 * n + lo;
#pragma unroll
            for (int jx = 0; jx < 4; ++jx) {
                const int row = wave * 16 + hi * 4 + jx;
                const float p = (!fm && (kt < qb || col <= row)) ? __expf(acc[jx]) * il4[jx] : 0.f;
                Pf[row * PFLD + col] = p;
            }
        }
        {   // coalesced 256B-burst store of own band
            const int r = wave * 16 + (lane >> 2);
            const int cb = (lane & 3) * 16;
            float* dst = &Pg[((size_t)(b * SEQ) + q0 + r) * SEQ + kt * KT + cb];
            const float* src = &Pf[r * PFLD + cb];
#pragma unroll
            for (int iw = 0; iw < 4; ++iw)
                *(f32x4*)&dst[4 * iw] = *(const f32x4*)&src[4 * iw];
        }
    }
}

extern "C" void kernel_launch(void* const* d_in, const int* in_sizes, int n_in,
                              void* d_out, int out_size, void* d_ws, size_t ws_size,
                              hipStream_t stream) {
    const float* q = (const float*)d_in[0];
    const float* k = (const float*)d_in[1];
    const float* v = (const float*)d_in[2];
    float* out  = (float*)d_out;                        // [B,T,D] fp32
    float* smqk = out + (size_t)BATCHES * SEQ * DIM;    // [B,T,T] fp32
    float* ilW  = (float*)d_ws;                         // [B,T] fp32 (128 KB)

    attn_ol<<<NQB * BATCHES, 256, 0, stream>>>(q, k, v, out, smqk, ilW);
    emit_p<<<768, 256, 0, stream>>>(q, k, ilW, smqk);
}

// Round 9
// 145.089 us; speedup vs baseline: 1.0520x; 1.0172x over previous
//
#include <hip/hip_runtime.h>
#include <hip/hip_bf16.h>

// SDPA, causal, b=16 t=2048 d=64. Outputs FP32: d_out = [ out | sm_qk ].
// R9: single fused kernel, S computed ONCE.
//  Phase 1 (kt=0..qb): compensated S (6 MFMA), p=exp(S) rounded to bf16;
//    accumulate l from the ROUNDED p; PV accumulate O; stream the bf16 tile
//    into the sm_qk region packed (col c at byte 2c of the fp32 row).
//  Phase 2 (kt=31..0 DESCENDING): read back own bf16 band (L2-hot), scale by
//    il, expand to fp32 in place; kt>qb writes zeros. fp32 tile kt overwrites
//    bf16 tiles 2kt,2kt+1 -> already consumed in descending order; same-tile
//    ordering guaranteed by load->convert->store data dependency (wave-wide
//    vmcnt). Per-block phase-2 stores are exactly uniform (512 KB).
// XCD batch clustering + causal pairing as R5.

#define BATCHES 16
#define SEQ 2048
#define DIM 64
#define QB 64
#define KT 64
#define NQB (SEQ / QB) /* 32 */
#define KLD 72   /* K LDS row stride, shorts */
#define VLD 72   /* V^T LDS row stride, shorts */
#define PBLD 72  /* bf16 P-tile stride, shorts */

typedef __attribute__((ext_vector_type(8))) short bf16x8;
typedef __attribute__((ext_vector_type(4))) short short4v;
typedef __attribute__((ext_vector_type(4))) float f32x4;

static __device__ __forceinline__ short f2bf(float f) {
    return __builtin_bit_cast(short, __float2bfloat16(f));
}
static __device__ __forceinline__ float bf2f(short s) {
    unsigned int u = ((unsigned int)(unsigned short)s) << 16;
    return __builtin_bit_cast(float, u);
}
static __device__ __forceinline__ void split8(f32x4 a, f32x4 b, float sc,
                                              bf16x8& h, bf16x8& l) {
#pragma unroll
    for (int e = 0; e < 4; ++e) {
        float x = a[e] * sc;
        short hb = f2bf(x);
        h[e] = hb; l[e] = f2bf(x - bf2f(hb));
    }
#pragma unroll
    for (int e = 0; e < 4; ++e) {
        float x = b[e] * sc;
        short hb = f2bf(x);
        h[4 + e] = hb; l[4 + e] = f2bf(x - bf2f(hb));
    }
}

__global__ __launch_bounds__(256, 2) void sdpa_fused(
    const float* __restrict__ Qg, const float* __restrict__ Kg,
    const float* __restrict__ Vg, float* __restrict__ Og, float* __restrict__ Pg)
{
    const int i = blockIdx.x;
    const int g = i & 7;
    const int j = i >> 3;             // 0..63
    const int b = 2 * g + (j >> 5);
    const int jj = j & 31;
    const int qb = (j < 32) ? jj : (31 - jj);
    const int q0 = qb * QB;

    const int tid = threadIdx.x;
    const int lane = tid & 63;
    const int wave = tid >> 6;
    const int lo = lane & 15;
    const int hi = lane >> 4;
    const int sr = tid >> 4;
    const int sc = (tid & 15) * 4;
    const int vr = (tid >> 4) * 4;

    __shared__ short Khi[KT * KLD];
    __shared__ short Klo[KT * KLD];
    __shared__ short Vt[DIM * VLD];
    __shared__ short Pb[QB * PBLD];
    __shared__ float ilS[QB];

    const float* qB = Qg + (size_t)b * SEQ * DIM;
    const float* kB = Kg + (size_t)b * SEQ * DIM;
    const float* vB = Vg + (size_t)b * SEQ * DIM;

    bf16x8 qa0h, qa0l, qa1h, qa1l;
    {
        const float* qr = &qB[(size_t)(q0 + wave * 16 + lo) * DIM + hi * 8];
        split8(*(const f32x4*)qr,        *(const f32x4*)(qr + 4),  0.125f, qa0h, qa0l);
        split8(*(const f32x4*)(qr + 32), *(const f32x4*)(qr + 36), 0.125f, qa1h, qa1l);
    }

    const int nkt = qb + 1;
    float rl[4] = {0.f, 0.f, 0.f, 0.f};
    f32x4 o[4];
#pragma unroll
    for (int n = 0; n < 4; ++n) { o[n][0] = 0.f; o[n][1] = 0.f; o[n][2] = 0.f; o[n][3] = 0.f; }

    f32x4 kp[4], vp[4];
#pragma unroll
    for (int ii = 0; ii < 4; ++ii) {
        kp[ii] = *(const f32x4*)&kB[(size_t)(sr + 16 * ii) * DIM + sc];
        vp[ii] = *(const f32x4*)&vB[(size_t)(vr + ii) * DIM + sc];
    }

    // stripe coords for P streaming (own wave rows)
    const int r2l  = wave * 16 + (lane >> 2);           // global-band row
    const int cg2  = (lane & 3) * 16;                   // col group base
    const size_t rowbase = (size_t)(b * SEQ) + q0 + r2l;
    float* frow = Pg + rowbase * SEQ;
    short* srow = (short*)frow;                         // bf16 c at srow[c]

    // ================ phase 1 ================
    for (int kt = 0; kt < nkt; ++kt) {
        __syncthreads();
        {   // stage K (hi/lo) + V^T from prefetched regs
#pragma unroll
            for (int ii = 0; ii < 4; ++ii) {
                short4v hh, ll;
#pragma unroll
                for (int e = 0; e < 4; ++e) {
                    short hb = f2bf(kp[ii][e]);
                    hh[e] = hb; ll[e] = f2bf(kp[ii][e] - bf2f(hb));
                }
                *(short4v*)&Khi[(sr + 16 * ii) * KLD + sc] = hh;
                *(short4v*)&Klo[(sr + 16 * ii) * KLD + sc] = ll;
            }
#pragma unroll
            for (int e = 0; e < 4; ++e) {
                short4v tv;
#pragma unroll
                for (int ii = 0; ii < 4; ++ii) tv[ii] = f2bf(vp[ii][e]);
                *(short4v*)&Vt[(sc + e) * VLD + vr] = tv;
            }
        }
        __syncthreads();
        if (kt + 1 < nkt) {
#pragma unroll
            for (int ii = 0; ii < 4; ++ii) {
                kp[ii] = *(const f32x4*)&kB[(size_t)((kt + 1) * KT + sr + 16 * ii) * DIM + sc];
                vp[ii] = *(const f32x4*)&vB[(size_t)((kt + 1) * KT + vr + ii) * DIM + sc];
            }
        }
        // S (compensated) -> p = exp(S) rounded bf16; l += rounded; Pb relay
#pragma unroll
        for (int n = 0; n < 4; ++n) {
            const bool fm = (kt == qb) && (n > wave);
            f32x4 acc = {0.f, 0.f, 0.f, 0.f};
            if (!fm) {
                bf16x8 kh0 = *(const bf16x8*)&Khi[(16 * n + lo) * KLD + hi * 8];
                bf16x8 kh1 = *(const bf16x8*)&Khi[(16 * n + lo) * KLD + 32 + hi * 8];
                bf16x8 kl0 = *(const bf16x8*)&Klo[(16 * n + lo) * KLD + hi * 8];
                bf16x8 kl1 = *(const bf16x8*)&Klo[(16 * n + lo) * KLD + 32 + hi * 8];
                acc = __builtin_amdgcn_mfma_f32_16x16x32_bf16(qa0h, kh0, acc, 0, 0, 0);
                acc = __builtin_amdgcn_mfma_f32_16x16x32_bf16(qa1h, kh1, acc, 0, 0, 0);
                acc = __builtin_amdgcn_mfma_f32_16x16x32_bf16(qa0h, kl0, acc, 0, 0, 0);
                acc = __builtin_amdgcn_mfma_f32_16x16x32_bf16(qa1h, kl1, acc, 0, 0, 0);
                acc = __builtin_amdgcn_mfma_f32_16x16x32_bf16(qa0l, kh0, acc, 0, 0, 0);
                acc = __builtin_amdgcn_mfma_f32_16x16x32_bf16(qa1l, kh1, acc, 0, 0, 0);
            }
            const int col = 16 * n + lo;
#pragma unroll
            for (int jx = 0; jx < 4; ++jx) {
                const int row = wave * 16 + hi * 4 + jx;
                const float p = (!fm && (kt < qb || col <= row)) ? __expf(acc[jx]) : 0.f;
                const short pb = f2bf(p);
                rl[jx] += bf2f(pb);           // l from ROUNDED values
                Pb[row * PBLD + col] = pb;
            }
        }
        // O += P_unnorm * V
        {
            bf16x8 pa0 = *(const bf16x8*)&Pb[(wave * 16 + lo) * PBLD + hi * 8];
            bf16x8 pa1 = *(const bf16x8*)&Pb[(wave * 16 + lo) * PBLD + 32 + hi * 8];
#pragma unroll
            for (int n = 0; n < 4; ++n) {
                bf16x8 vb0 = *(const bf16x8*)&Vt[(16 * n + lo) * VLD + hi * 8];
                bf16x8 vb1 = *(const bf16x8*)&Vt[(16 * n + lo) * VLD + 32 + hi * 8];
                o[n] = __builtin_amdgcn_mfma_f32_16x16x32_bf16(pa0, vb0, o[n], 0, 0, 0);
                o[n] = __builtin_amdgcn_mfma_f32_16x16x32_bf16(pa1, vb1, o[n], 0, 0, 0);
            }
        }
        // stream bf16 P stripe packed into the sm_qk region (byte 2c of row)
        {
            *(bf16x8*)&srow[kt * KT + cg2]     = *(const bf16x8*)&Pb[r2l * PBLD + cg2];
            *(bf16x8*)&srow[kt * KT + cg2 + 8] = *(const bf16x8*)&Pb[r2l * PBLD + cg2 + 8];
        }
    }

    // ---- l -> il; share per-row via LDS; write O ----
#pragma unroll
    for (int m = 1; m <= 8; m <<= 1)
#pragma unroll
        for (int jx = 0; jx < 4; ++jx) rl[jx] += __shfl_xor(rl[jx], m, 16);
    float il[4];
#pragma unroll
    for (int jx = 0; jx < 4; ++jx) il[jx] = 1.0f / rl[jx];
    if (lo == 0) {
#pragma unroll
        for (int jx = 0; jx < 4; ++jx)
            ilS[wave * 16 + hi * 4 + jx] = il[jx];
    }
    {
        float* og = &Og[((size_t)(b * SEQ) + q0 + wave * 16 + hi * 4) * DIM + lo];
#pragma unroll
        for (int jx = 0; jx < 4; ++jx)
#pragma unroll
            for (int n = 0; n < 4; ++n)
                og[jx * DIM + n * 16] = o[n][jx] * il[jx];
    }

    // all bf16 stores visible before readback (same-wave store->load)
    asm volatile("s_waitcnt vmcnt(0)" ::: "memory");

    // ================ phase 2: expand bf16 -> normalized fp32 ================
    {
        const float ilr = ilS[r2l];   // same-wave LDS write, lgkm-ordered
        for (int kt = NQB - 1; kt >= 0; --kt) {
            float* dst = frow + kt * KT + cg2;
            if (kt <= qb) {
                bf16x8 a = *(const bf16x8*)&srow[kt * KT + cg2];
                bf16x8 c = *(const bf16x8*)&srow[kt * KT + cg2 + 8];
                f32x4 w0, w1, w2, w3;
#pragma unroll
                for (int e = 0; e < 4; ++e) {
                    w0[e] = bf2f(a[e]) * ilr;
                    w1[e] = bf2f(a[4 + e]) * ilr;
                    w2[e] = bf2f(c[e]) * ilr;
                    w3[e] = bf2f(c[4 + e]) * ilr;
                }
                *(f32x4*)dst = w0; *(f32x4*)(dst + 4) = w1;
                *(f32x4*)(dst + 8) = w2; *(f32x4*)(dst + 12) = w3;
            } else {
                const f32x4 z = {0.f, 0.f, 0.f, 0.f};
                *(f32x4*)dst = z; *(f32x4*)(dst + 4) = z;
                *(f32x4*)(dst + 8) = z; *(f32x4*)(dst + 12) = z;
            }
        }
    }
}

extern "C" void kernel_launch(void* const* d_in, const int* in_sizes, int n_in,
                              void* d_out, int out_size, void* d_ws, size_t ws_size,
                              hipStream_t stream) {
    const float* q = (const float*)d_in[0];
    const float* k = (const float*)d_in[1];
    const float* v = (const float*)d_in[2];
    float* out  = (float*)d_out;                        // [B,T,D] fp32
    float* smqk = out + (size_t)BATCHES * SEQ * DIM;    // [B,T,T] fp32

    sdpa_fused<<<NQB * BATCHES, 256, 0, stream>>>(q, k, v, out, smqk);
}

// Round 10
// 105.243 us; speedup vs baseline: 1.4503x; 1.3786x over previous
//
#include <hip/hip_runtime.h>
#include <hip/hip_bf16.h>

// SDPA, causal, b=16 t=2048 d=64. Outputs FP32: d_out = [ out | sm_qk ].
// R10 = R5 + LDS double-buffering (ONE barrier/iter; stage overlaps compute)
//       + depth-2 register prefetch + s_setprio around MFMA clusters.
// Phase 1: lean rowsum (uncompensated QK^T, Khi dbuf only).
// Phase 2: compensated QK^T (qh*kh+qh*kl+ql*kh), P=exp*il fp32 via LDS tile,
//          PV via transposed-V LDS; all three tile sets double-buffered.
// XCD batch clustering: block i -> XCD i%8; XCD g owns batches {2g,2g+1};
// causal pairing (qb=c with qb=31-c) balances per-CU work.

#define BATCHES 16
#define SEQ 2048
#define DIM 64
#define QB 64
#define KT 64
#define NQB (SEQ / QB) /* 32 */
#define KLD 72   /* K LDS row stride, shorts */
#define VLD 72   /* V^T LDS row stride, shorts */
#define PFLD 68  /* fp32 P-tile stride, floats */

typedef __attribute__((ext_vector_type(8))) short bf16x8;
typedef __attribute__((ext_vector_type(4))) short short4v;
typedef __attribute__((ext_vector_type(4))) float f32x4;

static __device__ __forceinline__ short f2bf(float f) {
    return __builtin_bit_cast(short, __float2bfloat16(f));
}
static __device__ __forceinline__ float bf2f(short s) {
    unsigned int u = ((unsigned int)(unsigned short)s) << 16;
    return __builtin_bit_cast(float, u);
}
static __device__ __forceinline__ void split8(f32x4 a, f32x4 b, float sc,
                                              bf16x8& h, bf16x8& l) {
#pragma unroll
    for (int e = 0; e < 4; ++e) {
        float x = a[e] * sc;
        short hb = f2bf(x);
        h[e] = hb; l[e] = f2bf(x - bf2f(hb));
    }
#pragma unroll
    for (int e = 0; e < 4; ++e) {
        float x = b[e] * sc;
        short hb = f2bf(x);
        h[4 + e] = hb; l[4 + e] = f2bf(x - bf2f(hb));
    }
}

__global__ __launch_bounds__(256, 2) void sdpa_fused(
    const float* __restrict__ Qg, const float* __restrict__ Kg,
    const float* __restrict__ Vg, float* __restrict__ Og, float* __restrict__ Pg)
{
    const int i = blockIdx.x;
    const int g = i & 7;
    const int j = i >> 3;             // 0..63
    const int b = 2 * g + (j >> 5);
    const int jj = j & 31;
    const int qb = (j < 32) ? jj : (31 - jj);
    const int q0 = qb * QB;

    const int tid = threadIdx.x;
    const int lane = tid & 63;
    const int wave = tid >> 6;
    const int lo = lane & 15;
    const int hi = lane >> 4;
    const int sr = tid >> 4;          // K stage rows: sr+16*ii
    const int sc = (tid & 15) * 4;    // stage col
    const int vr = (tid >> 4) * 4;    // V stage rows: vr..vr+3

    __shared__ short Khi[2][KT * KLD];
    __shared__ short Klo[2][KT * KLD];
    __shared__ short Vt [2][DIM * VLD];
    __shared__ float Pf[QB * PFLD];   // wave-private bands, no cross-wave sync

    const float* qB = Qg + (size_t)b * SEQ * DIM;
    const float* kB = Kg + (size_t)b * SEQ * DIM;
    const float* vB = Vg + (size_t)b * SEQ * DIM;

    bf16x8 qa0h, qa0l, qa1h, qa1l;
    {
        const float* qr = &qB[(size_t)(q0 + wave * 16 + lo) * DIM + hi * 8];
        split8(*(const f32x4*)qr,        *(const f32x4*)(qr + 4),  0.125f, qa0h, qa0l);
        split8(*(const f32x4*)(qr + 32), *(const f32x4*)(qr + 36), 0.125f, qa1h, qa1l);
    }

    const int nkt = qb + 1;
    float rl[4] = {0.f, 0.f, 0.f, 0.f};

    auto loadK = [&](f32x4* kp, int kt) {
#pragma unroll
        for (int ii = 0; ii < 4; ++ii)
            kp[ii] = *(const f32x4*)&kB[(size_t)(kt * KT + sr + 16 * ii) * DIM + sc];
    };
    auto loadV = [&](f32x4* vp, int kt) {
#pragma unroll
        for (int ii = 0; ii < 4; ++ii)
            vp[ii] = *(const f32x4*)&vB[(size_t)(kt * KT + vr + ii) * DIM + sc];
    };
    auto stageKhi = [&](int buf, const f32x4* kp) {
#pragma unroll
        for (int ii = 0; ii < 4; ++ii) {
            short4v hh;
#pragma unroll
            for (int e = 0; e < 4; ++e) hh[e] = f2bf(kp[ii][e]);
            *(short4v*)&Khi[buf][(sr + 16 * ii) * KLD + sc] = hh;
        }
    };
    auto stageKsplit = [&](int buf, const f32x4* kp) {
#pragma unroll
        for (int ii = 0; ii < 4; ++ii) {
            short4v hh, ll;
#pragma unroll
            for (int e = 0; e < 4; ++e) {
                short hb = f2bf(kp[ii][e]);
                hh[e] = hb; ll[e] = f2bf(kp[ii][e] - bf2f(hb));
            }
            *(short4v*)&Khi[buf][(sr + 16 * ii) * KLD + sc] = hh;
            *(short4v*)&Klo[buf][(sr + 16 * ii) * KLD + sc] = ll;
        }
    };
    auto stageVt = [&](int buf, const f32x4* vp) {
#pragma unroll
        for (int e = 0; e < 4; ++e) {
            short4v tv;
#pragma unroll
            for (int ii = 0; ii < 4; ++ii) tv[ii] = f2bf(vp[ii][e]);
            *(short4v*)&Vt[buf][(sc + e) * VLD + vr] = tv;
        }
    };

    // ================ phase 1: l = sum exp(S), lean ================
    {
        f32x4 kp[4];
        loadK(kp, 0);
        stageKhi(0, kp);
        if (nkt > 1) loadK(kp, 1);
        __syncthreads();
        for (int kt = 0; kt < nkt; ++kt) {
            const int cur = kt & 1;
            if (kt + 1 < nkt) {
                stageKhi(cur ^ 1, kp);          // overlaps with compute below
                if (kt + 2 < nkt) loadK(kp, kt + 2);
            }
            const int nmax = (kt == qb) ? (wave + 1) : 4;
            for (int n = 0; n < nmax; ++n) {
                bf16x8 kh0 = *(const bf16x8*)&Khi[cur][(16 * n + lo) * KLD + hi * 8];
                bf16x8 kh1 = *(const bf16x8*)&Khi[cur][(16 * n + lo) * KLD + 32 + hi * 8];
                f32x4 acc = {0.f, 0.f, 0.f, 0.f};
                __builtin_amdgcn_s_setprio(1);
                acc = __builtin_amdgcn_mfma_f32_16x16x32_bf16(qa0h, kh0, acc, 0, 0, 0);
                acc = __builtin_amdgcn_mfma_f32_16x16x32_bf16(qa1h, kh1, acc, 0, 0, 0);
                __builtin_amdgcn_s_setprio(0);
                if (kt < qb) {
#pragma unroll
                    for (int jx = 0; jx < 4; ++jx) rl[jx] += __expf(acc[jx]);
                } else {
                    const int col = 16 * n + lo;
#pragma unroll
                    for (int jx = 0; jx < 4; ++jx)
                        if (col <= wave * 16 + hi * 4 + jx) rl[jx] += __expf(acc[jx]);
                }
            }
            __syncthreads();
        }
    }
#pragma unroll
    for (int m = 1; m <= 8; m <<= 1)
#pragma unroll
        for (int jx = 0; jx < 4; ++jx) rl[jx] += __shfl_xor(rl[jx], m, 16);
    float il[4];
#pragma unroll
    for (int jx = 0; jx < 4; ++jx) il[jx] = 1.0f / rl[jx];

    // ============ phase 2: P = exp(S)*il (fp32) + O = P*V ============
    f32x4 o[4];
#pragma unroll
    for (int n = 0; n < 4; ++n) { o[n][0] = 0.f; o[n][1] = 0.f; o[n][2] = 0.f; o[n][3] = 0.f; }

    {
        f32x4 kp[4], vp[4];
        loadK(kp, 0); loadV(vp, 0);
        stageKsplit(0, kp); stageVt(0, vp);
        if (nkt > 1) { loadK(kp, 1); loadV(vp, 1); }
        __syncthreads();

        for (int kt = 0; kt < nkt; ++kt) {
            const int cur = kt & 1;
            if (kt + 1 < nkt) {
                stageKsplit(cur ^ 1, kp);
                stageVt(cur ^ 1, vp);
                if (kt + 2 < nkt) { loadK(kp, kt + 2); loadV(vp, kt + 2); }
            }
            // S = QK^T (compensated) -> Pf (wave-private band)
#pragma unroll
            for (int n = 0; n < 4; ++n) {
                const bool fm = (kt == qb) && (n > wave);  // wave-uniform
                f32x4 acc = {0.f, 0.f, 0.f, 0.f};
                if (!fm) {
                    bf16x8 kh0 = *(const bf16x8*)&Khi[cur][(16 * n + lo) * KLD + hi * 8];
                    bf16x8 kh1 = *(const bf16x8*)&Khi[cur][(16 * n + lo) * KLD + 32 + hi * 8];
                    bf16x8 kl0 = *(const bf16x8*)&Klo[cur][(16 * n + lo) * KLD + hi * 8];
                    bf16x8 kl1 = *(const bf16x8*)&Klo[cur][(16 * n + lo) * KLD + 32 + hi * 8];
                    __builtin_amdgcn_s_setprio(1);
                    acc = __builtin_amdgcn_mfma_f32_16x16x32_bf16(qa0h, kh0, acc, 0, 0, 0);
                    acc = __builtin_amdgcn_mfma_f32_16x16x32_bf16(qa1h, kh1, acc, 0, 0, 0);
                    acc = __builtin_amdgcn_mfma_f32_16x16x32_bf16(qa0h, kl0, acc, 0, 0, 0);
                    acc = __builtin_amdgcn_mfma_f32_16x16x32_bf16(qa1h, kl1, acc, 0, 0, 0);
                    acc = __builtin_amdgcn_mfma_f32_16x16x32_bf16(qa0l, kh0, acc, 0, 0, 0);
                    acc = __builtin_amdgcn_mfma_f32_16x16x32_bf16(qa1l, kh1, acc, 0, 0, 0);
                    __builtin_amdgcn_s_setprio(0);
                }
                const int col = 16 * n + lo;
#pragma unroll
                for (int jx = 0; jx < 4; ++jx) {
                    const int row = wave * 16 + hi * 4 + jx;
                    const float p = (!fm && (kt < qb || col <= row)) ? __expf(acc[jx]) * il[jx] : 0.f;
                    Pf[row * PFLD + col] = p;
                }
            }
            // stream own P band: per-instruction 64B-contiguous per 4-lane group
            {
                const int r = wave * 16 + (lane >> 2);
                const int c4 = (lane & 3) * 4;
                float* dst = &Pg[((size_t)(b * SEQ) + q0 + r) * SEQ + kt * KT + c4];
                const float* src = &Pf[r * PFLD + c4];
#pragma unroll
                for (int iw = 0; iw < 4; ++iw)
                    *(f32x4*)&dst[16 * iw] = *(const f32x4*)&src[16 * iw];
            }
            // PV: A-frag from own Pf band, B-frag from Vt[cur]
            {
                const float* pr = &Pf[(wave * 16 + lo) * PFLD + hi * 8];
                bf16x8 pa0, pa1;
                {
                    f32x4 a = *(const f32x4*)pr, c2 = *(const f32x4*)(pr + 4);
                    f32x4 d = *(const f32x4*)(pr + 32), e2 = *(const f32x4*)(pr + 36);
#pragma unroll
                    for (int e = 0; e < 4; ++e) {
                        pa0[e] = f2bf(a[e]); pa0[4 + e] = f2bf(c2[e]);
                        pa1[e] = f2bf(d[e]); pa1[4 + e] = f2bf(e2[e]);
                    }
                }
                __builtin_amdgcn_s_setprio(1);
#pragma unroll
                for (int n = 0; n < 4; ++n) {
                    bf16x8 vb0 = *(const bf16x8*)&Vt[cur][(16 * n + lo) * VLD + hi * 8];
                    bf16x8 vb1 = *(const bf16x8*)&Vt[cur][(16 * n + lo) * VLD + 32 + hi * 8];
                    o[n] = __builtin_amdgcn_mfma_f32_16x16x32_bf16(pa0, vb0, o[n], 0, 0, 0);
                    o[n] = __builtin_amdgcn_mfma_f32_16x16x32_bf16(pa1, vb1, o[n], 0, 0, 0);
                }
                __builtin_amdgcn_s_setprio(0);
            }
            __syncthreads();
        }
    }

    // ---- zero-fill fully-masked column tiles (exact 0 == ref underflow) ----
    {
        const int r = tid >> 2;
        float* rowp = &Pg[((size_t)(b * SEQ) + q0 + r) * SEQ];
        const f32x4 z = {0.f, 0.f, 0.f, 0.f};
        for (int cb = nkt * KT + (tid & 3) * 16; cb < SEQ; cb += KT)
#pragma unroll
            for (int iw = 0; iw < 4; ++iw)
                *(f32x4*)&rowp[cb + 4 * iw] = z;
    }
    // ---- O (already normalized: PV used exp*il), fp32 ----
    {
        float* og = &Og[((size_t)(b * SEQ) + q0 + wave * 16 + hi * 4) * DIM + lo];
#pragma unroll
        for (int jx = 0; jx < 4; ++jx)
#pragma unroll
            for (int n = 0; n < 4; ++n)
                og[jx * DIM + n * 16] = o[n][jx];
    }
}

extern "C" void kernel_launch(void* const* d_in, const int* in_sizes, int n_in,
                              void* d_out, int out_size, void* d_ws, size_t ws_size,
                              hipStream_t stream) {
    const float* q = (const float*)d_in[0];
    const float* k = (const float*)d_in[1];
    const float* v = (const float*)d_in[2];
    float* out  = (float*)d_out;                        // [B,T,D] fp32
    float* smqk = out + (size_t)BATCHES * SEQ * DIM;    // [B,T,T] fp32

    sdpa_fused<<<NQB * BATCHES, 256, 0, stream>>>(q, k, v, out, smqk);
}